// Round 4
// baseline (355.602 us; speedup 1.0000x reference)
//
#include <hip/hip_runtime.h>

#define TINY 1e-6f

constexpr int N_PIX  = 256 * 512;            // 131072 pixels, S = 64
constexpr int BLOCKS = 2048;                 // persistent-ish: 8 blocks/CU launched
constexpr int ITERS  = N_PIX / (BLOCKS * 16); // 4 pixel-quads per block

__device__ __forceinline__ float clamp01(float x) {
    return fminf(fmaxf(x, 0.0f), 1.0f);
}

__device__ __forceinline__ float frcp(float x) {
    return __builtin_amdgcn_rcpf(x);
}

__device__ __forceinline__ float cget(const float4& a, const float4& b, const float4& c, int i) {
    switch (i) {
        case 0:  return a.x; case 1:  return a.y; case 2:  return a.z; case 3:  return a.w;
        case 4:  return b.x; case 5:  return b.y; case 6:  return b.z; case 7:  return b.w;
        case 8:  return c.x; case 9:  return c.y; case 10: return c.z; default: return c.w;
    }
}

// one pipeline stage: everything a lane needs for its 4 samples of one pixel
struct Stage {
    float4 L0, L1, L2;   // light_dir_diff
    float4 D0, D1, D2;   // diffuse_lighting
    float4 H0, H1, H2;   // h_dir_specular
    float4 S0, S1, S2;   // specular_lighting
    float  nx, ny, nz;   // normal
    float  px, py, pz;   // point
    float  r;            // roughness
    float  ax, ay, az;   // albedo (used by sub==0 in epilogue)
};

__device__ __forceinline__ void load_stage(Stage& st, int pix, int sub,
        const float* __restrict__ normal, const float* __restrict__ albedo,
        const float* __restrict__ roughness, const float* __restrict__ points,
        const float* __restrict__ ldir, const float* __restrict__ dlight,
        const float* __restrict__ hdir, const float* __restrict__ slight)
{
    const size_t fb = (size_t)pix * 192 + (size_t)sub * 12;
    const float4* Lp = (const float4*)(ldir   + fb);
    const float4* Dp = (const float4*)(dlight + fb);
    const float4* Hp = (const float4*)(hdir   + fb);
    const float4* Sp = (const float4*)(slight + fb);
    st.L0 = Lp[0]; st.L1 = Lp[1]; st.L2 = Lp[2];
    st.D0 = Dp[0]; st.D1 = Dp[1]; st.D2 = Dp[2];
    st.H0 = Hp[0]; st.H1 = Hp[1]; st.H2 = Hp[2];
    st.S0 = Sp[0]; st.S1 = Sp[1]; st.S2 = Sp[2];
    st.nx = normal[pix * 3 + 0];
    st.ny = normal[pix * 3 + 1];
    st.nz = normal[pix * 3 + 2];
    st.px = points[pix * 3 + 0];
    st.py = points[pix * 3 + 1];
    st.pz = points[pix * 3 + 2];
    st.r  = roughness[pix];
    st.ax = albedo[pix * 3 + 0];
    st.ay = albedo[pix * 3 + 1];
    st.az = albedo[pix * 3 + 2];
}

__global__ void __launch_bounds__(256)
shade_kernel(const float* __restrict__ normal,
             const float* __restrict__ albedo,
             const float* __restrict__ roughness,
             const float* __restrict__ points,
             const float* __restrict__ cam,
             const float* __restrict__ ldir,
             const float* __restrict__ dlight,
             const float* __restrict__ hdir,
             const float* __restrict__ slight,
             float* __restrict__ out)
{
    const int t   = threadIdx.x;
    const int grp = t >> 4;          // 16 pixel-groups per block
    const int sub = t & 15;          // lane-in-group: samples 4*sub .. 4*sub+3

    const float cx = cam[0], cy = cam[1], cz = cam[2];

    Stage A, B;
    {
        const int pix0 = (blockIdx.x * ITERS + 0) * 16 + grp;
        load_stage(A, pix0, sub, normal, albedo, roughness, points,
                   ldir, dlight, hdir, slight);
    }

#pragma unroll 1
    for (int it = 0; it < ITERS; ++it) {
        // prefetch next quad while computing on current (fine-grained vmcnt)
        if (it + 1 < ITERS) {
            const int pixn = (blockIdx.x * ITERS + (it + 1)) * 16 + grp;
            load_stage(B, pixn, sub, normal, albedo, roughness, points,
                       ldir, dlight, hdir, slight);
        }

        const int pix = (blockIdx.x * ITERS + it) * 16 + grp;

        // view = normalize(cam - p)
        const float dx = cx - A.px, dy = cy - A.py, dz = cz - A.pz;
        const float len = sqrtf(dx * dx + dy * dy + dz * dz);
        const float inv = frcp(fmaxf(len, 1e-4f));
        const float vx = dx * inv, vy = dy * inv, vz = dz * inv;

        const float ndv = clamp01(A.nx * vx + A.ny * vy + A.nz * vz);
        const float k   = (A.r + 1.0f) * (A.r + 1.0f) * 0.125f;
        const float omk = 1.0f - k;
        const float g1v = ndv * frcp(fmaxf(ndv * omk + k, TINY));

        float dacc0 = 0.f, dacc1 = 0.f, dacc2 = 0.f;
        float sacc0 = 0.f, sacc1 = 0.f, sacc2 = 0.f;

#pragma unroll
        for (int j = 0; j < 4; ++j) {
            const int e = j * 3;
            const float lx = cget(A.L0, A.L1, A.L2, e + 0);
            const float ly = cget(A.L0, A.L1, A.L2, e + 1);
            const float lz = cget(A.L0, A.L1, A.L2, e + 2);
            const float d0 = cget(A.D0, A.D1, A.D2, e + 0);
            const float d1 = cget(A.D0, A.D1, A.D2, e + 1);
            const float d2 = cget(A.D0, A.D1, A.D2, e + 2);
            const float hx = cget(A.H0, A.H1, A.H2, e + 0);
            const float hy = cget(A.H0, A.H1, A.H2, e + 1);
            const float hz = cget(A.H0, A.H1, A.H2, e + 2);
            const float s0 = cget(A.S0, A.S1, A.S2, e + 0);
            const float s1 = cget(A.S0, A.S1, A.S2, e + 1);
            const float s2 = cget(A.S0, A.S1, A.S2, e + 2);

            const float ndl_d = clamp01(A.nx * lx + A.ny * ly + A.nz * lz);
            dacc0 += d0 * ndl_d;
            dacc1 += d1 * ndl_d;
            dacc2 += d2 * ndl_d;

            const float vdh = clamp01(hx * vx + hy * vy + hz * vz);
            const float tv  = 2.0f * vdh;
            const float lsx = tv * hx - vx;
            const float lsy = tv * hy - vy;
            const float lsz = tv * hz - vz;
            const float ndl = clamp01(A.nx * lsx + A.ny * lsy + A.nz * lsz);
            const float ndh = clamp01(A.nx * hx + A.ny * hy + A.nz * hz);
            const float f   = 0.04f + 0.96f * exp2f((-5.55472f * vdh - 6.98316f) * vdh);
            const float g1l = ndl * frcp(fmaxf(ndl * omk + k, TINY));
            const float brdf = f * g1l * g1v * frcp(fmaxf(4.0f * ndl * ndv, TINY));
            const float w    = brdf * ndl * 4.0f * vdh * frcp(fmaxf(ndh, TINY));
            sacc0 += s0 * w;
            sacc1 += s1 * w;
            sacc2 += s2 * w;
        }

        // butterfly reduction within each 16-lane group
#pragma unroll
        for (int off = 1; off < 16; off <<= 1) {
            dacc0 += __shfl_xor(dacc0, off);
            dacc1 += __shfl_xor(dacc1, off);
            dacc2 += __shfl_xor(dacc2, off);
            sacc0 += __shfl_xor(sacc0, off);
            sacc1 += __shfl_xor(sacc1, off);
            sacc2 += __shfl_xor(sacc2, off);
        }

        if (sub == 0) {
            const float inv_s = 1.0f / 64.0f;
            out[pix * 3 + 0] = (dacc0 * A.ax * 2.0f + sacc0) * inv_s;
            out[pix * 3 + 1] = (dacc1 * A.ay * 2.0f + sacc1) * inv_s;
            out[pix * 3 + 2] = (dacc2 * A.az * 2.0f + sacc2) * inv_s;
        }

        A = B;  // advance pipeline (register copy, cheap)
    }
}

extern "C" void kernel_launch(void* const* d_in, const int* in_sizes, int n_in,
                              void* d_out, int out_size, void* d_ws, size_t ws_size,
                              hipStream_t stream) {
    const float* normal    = (const float*)d_in[0];
    const float* albedo    = (const float*)d_in[1];
    const float* roughness = (const float*)d_in[2];
    const float* points    = (const float*)d_in[3];
    const float* cam       = (const float*)d_in[4];
    const float* ldir      = (const float*)d_in[5];
    const float* dlight    = (const float*)d_in[6];
    const float* hdir      = (const float*)d_in[7];
    const float* slight    = (const float*)d_in[8];
    float* out = (float*)d_out;

    shade_kernel<<<BLOCKS, 256, 0, stream>>>(normal, albedo, roughness, points,
                                             cam, ldir, dlight, hdir, slight, out);
}

// Round 5
// 344.763 us; speedup vs baseline: 1.0314x; 1.0314x over previous
//
#include <hip/hip_runtime.h>

#define TINY 1e-6f

constexpr int N_PIX = 256 * 512;   // 131072 pixels, S = 64 samples

typedef unsigned int u32;

__device__ __forceinline__ float clamp01(float x) {
    return fminf(fmaxf(x, 0.0f), 1.0f);
}

__device__ __forceinline__ float frcp(float x) {
    return __builtin_amdgcn_rcpf(x);
}

// async global->LDS DMA, 16 B per lane. lds dest must be wave-uniform base;
// HW scatters lane i to base + 16*i. gptr is per-lane (base + 16*lane).
__device__ __forceinline__ void dma16(const float* g, float* l) {
    __builtin_amdgcn_global_load_lds(
        (const __attribute__((address_space(1))) u32*)g,
        (__attribute__((address_space(3))) u32*)l, 16, 0, 0);
}

__device__ __forceinline__ float cget(const float4& a, const float4& b, const float4& c, int i) {
    switch (i) {
        case 0:  return a.x; case 1:  return a.y; case 2:  return a.z; case 3:  return a.w;
        case 4:  return b.x; case 5:  return b.y; case 6:  return b.z; case 7:  return b.w;
        case 8:  return c.x; case 9:  return c.y; case 10: return c.z; default: return c.w;
    }
}

__global__ void __launch_bounds__(256)
shade_kernel(const float* __restrict__ normal,
             const float* __restrict__ albedo,
             const float* __restrict__ roughness,
             const float* __restrict__ points,
             const float* __restrict__ cam,
             const float* __restrict__ ldir,
             const float* __restrict__ dlight,
             const float* __restrict__ hdir,
             const float* __restrict__ slight,
             float* __restrict__ out)
{
    // 48 KB: 4 arrays x 16 pixels x 192 floats, array-major then natural order
    __shared__ float lds[4 * 3072];

    const int t    = threadIdx.x;
    const int w    = t >> 6;        // wave 0..3
    const int lane = t & 63;
    const int stage0 = blockIdx.x * 16;   // first pixel of this block's tile

    // ---- issue 12 DMA instructions per wave: fully coalesced 1 KB each ----
    // per array: 12 chunks of 256 floats (1024 B); wave w owns chunks 3w..3w+2
    {
        const size_t gbase = (size_t)stage0 * 192;
        const float* garr[4] = { ldir, dlight, hdir, slight };
#pragma unroll
        for (int a = 0; a < 4; ++a) {
#pragma unroll
            for (int c = 0; c < 3; ++c) {
                const int chunk = w * 3 + c;              // 0..11
                const int foff  = chunk * 256;            // floats within tile
                dma16(garr[a] + gbase + foff + lane * 4,  // per-lane global addr
                      &lds[a * 3072 + foff]);             // wave-uniform LDS base
            }
        }
    }

    // ---- per-pixel constants (overlap with DMA in flight) ----
    const int grp = lane >> 4;            // 0..3: pixel-in-wave
    const int sub = lane & 15;            // lane-in-group: samples 4*sub..4*sub+3
    const int pin = w * 4 + grp;          // pixel index within stage (0..15)
    const int pix = stage0 + pin;

    const float nx = normal[pix * 3 + 0];
    const float ny = normal[pix * 3 + 1];
    const float nz = normal[pix * 3 + 2];
    const float r  = roughness[pix];
    const float px = points[pix * 3 + 0];
    const float py = points[pix * 3 + 1];
    const float pz = points[pix * 3 + 2];
    const float cx = cam[0], cy = cam[1], cz = cam[2];

    const float dx = cx - px, dy = cy - py, dz = cz - pz;
    const float len = sqrtf(dx * dx + dy * dy + dz * dz);
    const float inv = frcp(fmaxf(len, 1e-4f));
    const float vx = dx * inv, vy = dy * inv, vz = dz * inv;

    const float ndv = clamp01(nx * vx + ny * vy + nz * vz);
    const float k   = (r + 1.0f) * (r + 1.0f) * 0.125f;
    const float omk = 1.0f - k;
    const float g1v = ndv * frcp(fmaxf(ndv * omk + k, TINY));

    // ---- wait DMA + barrier (waves loaded each other's pixels) ----
    asm volatile("s_waitcnt vmcnt(0)" ::: "memory");
    __syncthreads();

    // ---- compute from LDS: 12 ds_read_b128 per lane ----
    const int lbase = pin * 192 + sub * 12;   // floats within each array tile
    const float4* Lp = (const float4*)&lds[0 * 3072 + lbase];
    const float4* Dp = (const float4*)&lds[1 * 3072 + lbase];
    const float4* Hp = (const float4*)&lds[2 * 3072 + lbase];
    const float4* Sp = (const float4*)&lds[3 * 3072 + lbase];
    const float4 L0 = Lp[0], L1 = Lp[1], L2 = Lp[2];
    const float4 D0 = Dp[0], D1 = Dp[1], D2 = Dp[2];
    const float4 H0 = Hp[0], H1 = Hp[1], H2 = Hp[2];
    const float4 S0 = Sp[0], S1 = Sp[1], S2 = Sp[2];

    float dacc0 = 0.f, dacc1 = 0.f, dacc2 = 0.f;
    float sacc0 = 0.f, sacc1 = 0.f, sacc2 = 0.f;

#pragma unroll
    for (int j = 0; j < 4; ++j) {
        const int e = j * 3;
        const float lx = cget(L0, L1, L2, e + 0);
        const float ly = cget(L0, L1, L2, e + 1);
        const float lz = cget(L0, L1, L2, e + 2);
        const float d0 = cget(D0, D1, D2, e + 0);
        const float d1 = cget(D0, D1, D2, e + 1);
        const float d2 = cget(D0, D1, D2, e + 2);
        const float hx = cget(H0, H1, H2, e + 0);
        const float hy = cget(H0, H1, H2, e + 1);
        const float hz = cget(H0, H1, H2, e + 2);
        const float s0 = cget(S0, S1, S2, e + 0);
        const float s1 = cget(S0, S1, S2, e + 1);
        const float s2 = cget(S0, S1, S2, e + 2);

        const float ndl_d = clamp01(nx * lx + ny * ly + nz * lz);
        dacc0 += d0 * ndl_d;
        dacc1 += d1 * ndl_d;
        dacc2 += d2 * ndl_d;

        const float vdh = clamp01(hx * vx + hy * vy + hz * vz);
        const float tv  = 2.0f * vdh;
        const float lsx = tv * hx - vx;
        const float lsy = tv * hy - vy;
        const float lsz = tv * hz - vz;
        const float ndl = clamp01(nx * lsx + ny * lsy + nz * lsz);
        const float ndh = clamp01(nx * hx + ny * hy + nz * hz);
        const float f   = 0.04f + 0.96f * exp2f((-5.55472f * vdh - 6.98316f) * vdh);
        const float g1l = ndl * frcp(fmaxf(ndl * omk + k, TINY));
        const float brdf = f * g1l * g1v * frcp(fmaxf(4.0f * ndl * ndv, TINY));
        const float wgt  = brdf * ndl * 4.0f * vdh * frcp(fmaxf(ndh, TINY));
        sacc0 += s0 * wgt;
        sacc1 += s1 * wgt;
        sacc2 += s2 * wgt;
    }

    // ---- butterfly reduction within each 16-lane group ----
#pragma unroll
    for (int off = 1; off < 16; off <<= 1) {
        dacc0 += __shfl_xor(dacc0, off);
        dacc1 += __shfl_xor(dacc1, off);
        dacc2 += __shfl_xor(dacc2, off);
        sacc0 += __shfl_xor(sacc0, off);
        sacc1 += __shfl_xor(sacc1, off);
        sacc2 += __shfl_xor(sacc2, off);
    }

    if (sub == 0) {
        const float ax = albedo[pix * 3 + 0];
        const float ay = albedo[pix * 3 + 1];
        const float az = albedo[pix * 3 + 2];
        const float inv_s = 1.0f / 64.0f;
        out[pix * 3 + 0] = (dacc0 * ax * 2.0f + sacc0) * inv_s;
        out[pix * 3 + 1] = (dacc1 * ay * 2.0f + sacc1) * inv_s;
        out[pix * 3 + 2] = (dacc2 * az * 2.0f + sacc2) * inv_s;
    }
}

extern "C" void kernel_launch(void* const* d_in, const int* in_sizes, int n_in,
                              void* d_out, int out_size, void* d_ws, size_t ws_size,
                              hipStream_t stream) {
    const float* normal    = (const float*)d_in[0];
    const float* albedo    = (const float*)d_in[1];
    const float* roughness = (const float*)d_in[2];
    const float* points    = (const float*)d_in[3];
    const float* cam       = (const float*)d_in[4];
    const float* ldir      = (const float*)d_in[5];
    const float* dlight    = (const float*)d_in[6];
    const float* hdir      = (const float*)d_in[7];
    const float* slight    = (const float*)d_in[8];
    float* out = (float*)d_out;

    // one 16-pixel stage per 256-thread block
    const int blocks = N_PIX / 16;  // 8192
    shade_kernel<<<blocks, 256, 0, stream>>>(normal, albedo, roughness, points,
                                             cam, ldir, dlight, hdir, slight, out);
}